// Round 15
// baseline (5664.886 us; speedup 1.0000x reference)
//
#include <hip/hip_runtime.h>

#define NK 256
#define BB 128
#define CC 10
#define LL 16384
#define EPSV 1e-10f
#define GS2 11
// XW must cover staging granularity: nit4*256 (<=6*256) and nitS*64 (<=22*64),
// NOT just stot (<=1344). R14 bug: XW=1344 overflowed into next wave's slice.
#define XW 1536
#define WROW 12

__device__ __forceinline__ void block_finish(int cnt, float mx,
                                             float* rm, int* rc,
                                             int Lout, float* out, int b, int k) {
    int tid = threadIdx.x;
    for (int off = 32; off; off >>= 1) {
        mx = fmaxf(mx, __shfl_down(mx, off));
        cnt += __shfl_down(cnt, off);
    }
    int wv = tid >> 6, ln = tid & 63;
    if (ln == 0) { rm[wv] = mx; rc[wv] = cnt; }
    __syncthreads();
    if (tid == 0) {
#pragma unroll
        for (int i = 1; i < 4; ++i) { mx = fmaxf(mx, rm[i]); cnt += rc[i]; }
        size_t o = (size_t)b * (2 * NK) + 2 * k;
        out[o] = (float)cnt / (float)Lout;
        out[o + 1] = mx;
    }
}

__global__ __launch_bounds__(256) void stats_kernel(const float* __restrict__ x,
                                                    float* __restrict__ wsf) {
    int row = blockIdx.x;
    const float4* x4 = (const float4*)(x + (size_t)row * LL);
    int tid = threadIdx.x;
    float s = 0.f, s2 = 0.f;
    for (int i = tid; i < LL / 4; i += 256) {
        float4 v = x4[i];
        s += v.x + v.y + v.z + v.w;
        s2 += v.x * v.x + v.y * v.y + v.z * v.z + v.w * v.w;
    }
    for (int off = 32; off; off >>= 1) {
        s += __shfl_down(s, off);
        s2 += __shfl_down(s2, off);
    }
    __shared__ float as_[4], as2_[4];
    int wv = tid >> 6, ln = tid & 63;
    if (ln == 0) { as_[wv] = s; as2_[wv] = s2; }
    __syncthreads();
    if (tid == 0) {
        float S = as_[0] + as_[1] + as_[2] + as_[3];
        float S2 = as2_[0] + as2_[1] + as2_[2] + as2_[3];
        float mean = S / (float)LL;
        float var = (S2 - (float)LL * mean * mean) / (float)(LL - 1);
        var = fmaxf(var, 0.f);
        float inv = 1.f / (sqrtf(var) + EPSV);
        wsf[row] = inv;
        wsf[1280 + row] = -mean * inv;
    }
}

__global__ __launch_bounds__(256) void prefix_kernel(const int* __restrict__ lengths,
                                                     const int* __restrict__ ncis,
                                                     int* __restrict__ wbase,
                                                     int* __restrict__ cbase) {
    __shared__ int s1[NK], s2[NK];
    int k = threadIdx.x;
    int v1 = lengths[k] * ncis[k];
    int v2 = ncis[k];
    s1[k] = v1; s2[k] = v2;
    for (int off = 1; off < NK; off <<= 1) {
        __syncthreads();
        int a = (k >= off) ? s1[k - off] : 0;
        int b = (k >= off) ? s2[k - off] : 0;
        __syncthreads();
        s1[k] += a; s2[k] += b;
    }
    __syncthreads();
    wbase[k] = s1[k] - v1;
    cbase[k] = s2[k] - v2;
}

// ====== S: d <= 64 — wave-private LDS, flat phase chain, 2-ahead prefetch ====
template <int LEN>
__device__ __forceinline__ void conv_S(
    const float* __restrict__ x, float* __restrict__ xw,
    const float* __restrict__ wsmR, const float* __restrict__ wsmS,
    const int* __restrict__ choff, const float* __restrict__ cinv,
    const float* __restrict__ csh,
    int d, int ms, int Lout, int nci, float biasE, float biasI,
    int wu, int lane, int& cnt, float& mx) {
    constexpr int W = GS2 + LEN - 1;
    const int qpt = 64 / d;
    const int MT = qpt * GS2;
    const int stot = d * (MT + LEN - 1);          // <= 1344
    const int nit4 = (stot + 3 + 255) >> 8;       // <= 6 (wave-uniform)
    const int nitS = (stot + 3 + 63) >> 6;        // <= 22 (wave-uniform)
    const int Qmax = (Lout + d - 1) / d;
    const int nqt = (Qmax + MT - 1) / MT;
    int qi = lane / d, rho = lane - qi * d;
    bool act = qi < qpt;
    int a0 = act ? qi * GS2 * d + rho : 0;

    float rvA[24], rvB[24];

    auto tbOf = [&](int j) { return (j * MT - ms) * d; };
    auto isInt = [&](int tb_) {
        int base = tb_ - (tb_ & 3);
        return (base >= 0) && (base + (nit4 << 8) <= LL);
    };
    auto pref = [&](float (&rv)[24], int c, int tb_) {
        int base = tb_ - (tb_ & 3);
        const float* xc = x + choff[c];
        if (isInt(tb_)) {
            const float* xp = xc + base + 4 * lane;
#pragma unroll
            for (int it = 0; it < 6; ++it)
                if (it < nit4) *(float4*)&rv[4 * it] = *(const float4*)(xp + (it << 8));
        } else {
#pragma unroll
            for (int it = 0; it < 22; ++it)
                if (it < nitS) {
                    int t = base + (it << 6) + lane;
                    t = t < 0 ? 0 : (t > LL - 1 ? LL - 1 : t);
                    rv[it] = xc[t];
                }
        }
    };
    auto wstage = [&](float (&rv)[24], int tb_, float inv, float sh) {
        int base = tb_ - (tb_ & 3);
        if (isInt(tb_)) {
#pragma unroll
            for (int it = 0; it < 6; ++it)
                if (it < nit4) *(float4*)&xw[4 * lane + (it << 8)] = *(const float4*)&rv[4 * it];
        } else {
#pragma unroll
            for (int it = 0; it < 22; ++it)
                if (it < nitS) {
                    int t = base + (it << 6) + lane;
                    float v = ((unsigned)t < (unsigned)LL) ? fmaf(rv[it], inv, sh) : 0.f;
                    xw[(it << 6) + lane] = v;
                }
        }
    };
    auto compute = [&](int cc, bool I, int off, float (&acc)[GS2]) {
        const float* wt = I ? wsmS : wsmR;
        float wreg[WROW];
        const float4* wv4 = (const float4*)&wt[cc * WROW];
#pragma unroll
        for (int u = 0; u < (LEN + 3) / 4; ++u) {
            float4 w4 = wv4[u];
            wreg[4 * u + 0] = w4.x; wreg[4 * u + 1] = w4.y;
            wreg[4 * u + 2] = w4.z; wreg[4 * u + 3] = w4.w;
        }
        float win[W];
        int a = off + a0;
#pragma unroll
        for (int i = 0; i < W; ++i) { win[i] = xw[a]; a += d; }
        __builtin_amdgcn_s_setprio(1);
#pragma unroll
        for (int jj = 0; jj < LEN; ++jj)
#pragma unroll
            for (int g = 0; g < GS2; ++g)
                acc[g] = fmaf(wreg[jj], win[g + jj], acc[g]);
        __builtin_amdgcn_s_setprio(0);
    };
    auto epilogue = [&](int jc, bool I, float (&acc)[GS2]) {
        float bt = I ? biasI : biasE;
        if (act) {
            int qb = jc * MT + qi * GS2;
            if ((qb + GS2) * d <= Lout) {
                float am = acc[0];
#pragma unroll
                for (int g = 1; g < GS2; ++g) am = fmaxf(am, acc[g]);
                mx = fmaxf(mx, am + bt);
                float nb = -bt;
#pragma unroll
                for (int g = 0; g < GS2; ++g) cnt += (acc[g] > nb) ? 1 : 0;
            } else {
#pragma unroll
                for (int g = 0; g < GS2; ++g) {
                    int t = (qb + g) * d + rho;
                    if (t < Lout) {
                        float y = acc[g] + bt;
                        cnt += (y > 0.f) ? 1 : 0;
                        mx = fmaxf(mx, y);
                    }
                }
            }
        }
    };

    int jc = wu, cc = 0;
    int jp = wu, cp = 0;
    auto adv = [&]() { ++cp; if (cp == nci) { cp = 0; jp += 4; } };

    if (jc >= nqt) return;

    pref(rvA, cp, tbOf(jp)); adv();
    if (jp < nqt) { pref(rvB, cp, tbOf(jp)); adv(); }

    float acc[GS2];
#pragma unroll
    for (int g = 0; g < GS2; ++g) acc[g] = 0.f;
    int tb = tbOf(jc); int off = tb & 3; bool I = isInt(tb);

    while (true) {
        // phase on buffer A
        wstage(rvA, tb, cinv[cc], csh[cc]);
        if (jp < nqt) { pref(rvA, cp, tbOf(jp)); adv(); }
        compute(cc, I, off, acc);
        ++cc;
        if (cc == nci) {
            epilogue(jc, I, acc);
            cc = 0; jc += 4;
            if (jc >= nqt) break;
#pragma unroll
            for (int g = 0; g < GS2; ++g) acc[g] = 0.f;
            tb = tbOf(jc); off = tb & 3; I = isInt(tb);
        }
        // phase on buffer B
        wstage(rvB, tb, cinv[cc], csh[cc]);
        if (jp < nqt) { pref(rvB, cp, tbOf(jp)); adv(); }
        compute(cc, I, off, acc);
        ++cc;
        if (cc == nci) {
            epilogue(jc, I, acc);
            cc = 0; jc += 4;
            if (jc >= nqt) break;
#pragma unroll
            for (int g = 0; g < GS2; ++g) acc[g] = 0.f;
            tb = tbOf(jc); off = tb & 3; I = isInt(tb);
        }
    }
}

// ====== T: d > 64 — register windows, flat index, triple-buffer interior ====
template <int LEN, int GG>
__device__ __forceinline__ void conv_T(
    const float* __restrict__ x,
    const float* __restrict__ wsmR, const float* __restrict__ wsmS,
    const int* __restrict__ choff, const float* __restrict__ cinv,
    const float* __restrict__ csh,
    int d, int ms, int Lout, int nci, float biasE, float biasI,
    int wu, int lane, int& cnt, float& mx) {
    constexpr int M = GG + LEN - 1;
    const int Qmax = (Lout + d - 1) / d;
    const int nqt = (Qmax + GG - 1) / GG;
    const int NT = d * nqt;

    for (int f0 = wu * 64; f0 < NT; f0 += 256) {
        int f = f0 + lane;
        bool active = f < NT;
        int fc = active ? f : NT - 1;
        unsigned qi = (unsigned)fc / (unsigned)d;
        int rho = fc - (int)qi * d;
        int qb0 = (int)qi * GG;
        int tl = (qb0 - ms) * d + rho;
        bool laneInt = (tl >= 0) && (tl + (M - 1) * d < LL);
        bool interior = __all(laneInt);
        float acc[GG];
#pragma unroll
        for (int g = 0; g < GG; ++g) acc[g] = 0.f;

        float rA[M], rB[M], rC[M];

        auto fmaW = [&](float (&r)[M], int c, const float* wt) {
            float wreg[WROW];
            const float4* wv4 = (const float4*)&wt[c * WROW];
#pragma unroll
            for (int u = 0; u < (LEN + 3) / 4; ++u) {
                float4 w4 = wv4[u];
                wreg[4 * u + 0] = w4.x; wreg[4 * u + 1] = w4.y;
                wreg[4 * u + 2] = w4.z; wreg[4 * u + 3] = w4.w;
            }
            __builtin_amdgcn_s_setprio(1);
#pragma unroll
            for (int jj = 0; jj < LEN; ++jj)
#pragma unroll
                for (int g = 0; g < GG; ++g)
                    acc[g] = fmaf(wreg[jj], r[g + jj], acc[g]);
            __builtin_amdgcn_s_setprio(0);
        };

        if (interior) {
            auto ldI = [&](float (&r)[M], int c) {
                const float* xc = x + choff[c];
                int t = tl;
#pragma unroll
                for (int m = 0; m < M; ++m) { r[m] = xc[t]; t += d; }
            };
            ldI(rA, 0);
            if (nci > 1) ldI(rB, 1);
            int ci = 0;
            while (true) {
                if (ci + 2 < nci) ldI(rC, ci + 2);
                fmaW(rA, ci, wsmS);
                ++ci; if (ci >= nci) break;
                if (ci + 2 < nci) ldI(rA, ci + 2);
                fmaW(rB, ci, wsmS);
                ++ci; if (ci >= nci) break;
                if (ci + 2 < nci) ldI(rB, ci + 2);
                fmaW(rC, ci, wsmS);
                ++ci; if (ci >= nci) break;
            }
        } else {
            auto ldE = [&](float (&r)[M], int c) {
                const float* xc = x + choff[c];
                int t = tl;
#pragma unroll
                for (int m = 0; m < M; ++m) {
                    int tc = t < 0 ? 0 : (t > LL - 1 ? LL - 1 : t);
                    r[m] = xc[tc]; t += d;
                }
            };
            auto nrm = [&](float (&r)[M], int c) {
                float inv = cinv[c], sh = csh[c];
                int t = tl;
#pragma unroll
                for (int m = 0; m < M; ++m) {
                    r[m] = ((unsigned)t < (unsigned)LL) ? fmaf(r[m], inv, sh) : 0.f;
                    t += d;
                }
            };
            ldE(rA, 0);
            int ci = 0;
            while (true) {
                if (ci + 1 < nci) ldE(rB, ci + 1);
                nrm(rA, ci);
                fmaW(rA, ci, wsmR);
                ++ci; if (ci >= nci) break;
                if (ci + 1 < nci) ldE(rA, ci + 1);
                nrm(rB, ci);
                fmaW(rB, ci, wsmR);
                ++ci; if (ci >= nci) break;
            }
        }

        float bt = interior ? biasI : biasE;
        if (active) {
            if ((qb0 + GG) * d <= Lout) {
                float am = acc[0];
#pragma unroll
                for (int g = 1; g < GG; ++g) am = fmaxf(am, acc[g]);
                mx = fmaxf(mx, am + bt);
                float nb = -bt;
#pragma unroll
                for (int g = 0; g < GG; ++g) cnt += (acc[g] > nb) ? 1 : 0;
            } else {
#pragma unroll
                for (int g = 0; g < GG; ++g) {
                    int t = (qb0 + g) * d + rho;
                    if (t < Lout) {
                        float y = acc[g] + bt;
                        cnt += (y > 0.f) ? 1 : 0;
                        mx = fmaxf(mx, y);
                    }
                }
            }
        }
    }
}

__global__ __launch_bounds__(256) void conv_kernel(
    const float* __restrict__ x, const float* __restrict__ weights,
    const float* __restrict__ biases,
    const int* __restrict__ lengths, const int* __restrict__ dil,
    const int* __restrict__ pad, const int* __restrict__ ncis,
    const int* __restrict__ chidx,
    const float* __restrict__ wsf, const int* __restrict__ wbase,
    const int* __restrict__ cbase, float* __restrict__ out) {
    int k = blockIdx.x, b = blockIdx.y;
    __shared__ __align__(16) float xl[4 * XW];
    __shared__ __align__(16) float wsmR[CC * WROW];
    __shared__ __align__(16) float wsmS[CC * WROW];
    __shared__ int choff[CC];
    __shared__ float cinv[CC], csh[CC];
    __shared__ float rm[4];
    __shared__ int rc[4];

    int tid = threadIdx.x;
    int len = lengths[k], d = dil[k], p = pad[k], nci = ncis[k];
    int wb = wbase[k], cb = cbase[k];

    if (tid < nci) {
        int ch = chidx[cb + tid];
        choff[tid] = (b * CC + ch) * LL;
        cinv[tid] = wsf[b * CC + ch];
        csh[tid] = wsf[1280 + b * CC + ch];
    }
    __syncthreads();
    for (int i = tid; i < nci * WROW; i += 256) {
        int ci = i / WROW, jj = i - ci * WROW;
        float wv = (jj < len) ? weights[wb + ci * len + jj] : 0.f;
        wsmR[i] = wv;
        wsmS[i] = wv * cinv[ci];
    }
    __syncthreads();

    float csum = 0.f;
    for (int ci = 0; ci < nci; ++ci) {
        float sw = 0.f;
        for (int jj = 0; jj < WROW; ++jj) sw += wsmR[ci * WROW + jj];
        csum += csh[ci] * sw;
    }

    int span = (len - 1) * d;
    int Lout = LL + 2 * p - span;
    int ms = p / d;
    float biasE = biases[k];
    float biasI = biasE + csum;
    int Qmax = (Lout + d - 1) / d;

    int wu = tid >> 6;
    int lane = tid & 63;
    float* xw = xl + wu * XW;
    int cnt = 0;
    float mx = -3.4e38f;

    if (d <= 64) {
        switch (len) {
            case 7:  conv_S<7>(x, xw, wsmR, wsmS, choff, cinv, csh, d, ms, Lout, nci, biasE, biasI, wu, lane, cnt, mx); break;
            case 9:  conv_S<9>(x, xw, wsmR, wsmS, choff, cinv, csh, d, ms, Lout, nci, biasE, biasI, wu, lane, cnt, mx); break;
            default: conv_S<11>(x, xw, wsmR, wsmS, choff, cinv, csh, d, ms, Lout, nci, biasE, biasI, wu, lane, cnt, mx); break;
        }
    } else if (Qmax > 12) {
        switch (len) {
            case 7:  conv_T<7, 12>(x, wsmR, wsmS, choff, cinv, csh, d, ms, Lout, nci, biasE, biasI, wu, lane, cnt, mx); break;
            case 9:  conv_T<9, 12>(x, wsmR, wsmS, choff, cinv, csh, d, ms, Lout, nci, biasE, biasI, wu, lane, cnt, mx); break;
            default: conv_T<11, 12>(x, wsmR, wsmS, choff, cinv, csh, d, ms, Lout, nci, biasE, biasI, wu, lane, cnt, mx); break;
        }
    } else {
        switch (len) {
            case 7:  conv_T<7, 4>(x, wsmR, wsmS, choff, cinv, csh, d, ms, Lout, nci, biasE, biasI, wu, lane, cnt, mx); break;
            case 9:  conv_T<9, 4>(x, wsmR, wsmS, choff, cinv, csh, d, ms, Lout, nci, biasE, biasI, wu, lane, cnt, mx); break;
            default: conv_T<11, 4>(x, wsmR, wsmS, choff, cinv, csh, d, ms, Lout, nci, biasE, biasI, wu, lane, cnt, mx); break;
        }
    }
    block_finish(cnt, mx, rm, rc, Lout, out, b, k);
}

extern "C" void kernel_launch(void* const* d_in, const int* in_sizes, int n_in,
                              void* d_out, int out_size, void* d_ws, size_t ws_size,
                              hipStream_t stream) {
    const float* x = (const float*)d_in[0];
    const float* weights = (const float*)d_in[1];
    const float* biases = (const float*)d_in[2];
    const int* lengths = (const int*)d_in[3];
    const int* dil = (const int*)d_in[4];
    const int* pad = (const int*)d_in[5];
    const int* ncis = (const int*)d_in[6];
    const int* chidx = (const int*)d_in[7];
    float* out = (float*)d_out;

    float* wsf = (float*)d_ws;
    int* wbase = (int*)((char*)d_ws + 2560 * sizeof(float));
    int* cbase = wbase + NK;

    stats_kernel<<<dim3(BB * CC), dim3(256), 0, stream>>>(x, wsf);
    prefix_kernel<<<dim3(1), dim3(256), 0, stream>>>(lengths, ncis, wbase, cbase);
    dim3 grid(NK, BB);
    conv_kernel<<<grid, dim3(256), 0, stream>>>(x, weights, biases, lengths, dil,
                                                pad, ncis, chidx, wsf, wbase,
                                                cbase, out);
}

// Round 16
// 2213.087 us; speedup vs baseline: 2.5597x; 2.5597x over previous
//
#include <hip/hip_runtime.h>

#define NK 256
#define BB 128
#define CC 10
#define LL 16384
#define EPSV 1e-10f
#define GS2 15
#define XW 1792
#define WROW 12

__device__ __forceinline__ void block_finish(int cnt, float mx,
                                             float* rm, int* rc,
                                             int Lout, float* out, int b, int k) {
    int tid = threadIdx.x;
    for (int off = 32; off; off >>= 1) {
        mx = fmaxf(mx, __shfl_down(mx, off));
        cnt += __shfl_down(cnt, off);
    }
    int wv = tid >> 6, ln = tid & 63;
    if (ln == 0) { rm[wv] = mx; rc[wv] = cnt; }
    __syncthreads();
    if (tid == 0) {
#pragma unroll
        for (int i = 1; i < 4; ++i) { mx = fmaxf(mx, rm[i]); cnt += rc[i]; }
        size_t o = (size_t)b * (2 * NK) + 2 * k;
        out[o] = (float)cnt / (float)Lout;
        out[o + 1] = mx;
    }
}

__global__ __launch_bounds__(256) void stats_kernel(const float* __restrict__ x,
                                                    float* __restrict__ wsf) {
    int row = blockIdx.x;
    const float4* x4 = (const float4*)(x + (size_t)row * LL);
    int tid = threadIdx.x;
    float s = 0.f, s2 = 0.f;
    for (int i = tid; i < LL / 4; i += 256) {
        float4 v = x4[i];
        s += v.x + v.y + v.z + v.w;
        s2 += v.x * v.x + v.y * v.y + v.z * v.z + v.w * v.w;
    }
    for (int off = 32; off; off >>= 1) {
        s += __shfl_down(s, off);
        s2 += __shfl_down(s2, off);
    }
    __shared__ float as_[4], as2_[4];
    int wv = tid >> 6, ln = tid & 63;
    if (ln == 0) { as_[wv] = s; as2_[wv] = s2; }
    __syncthreads();
    if (tid == 0) {
        float S = as_[0] + as_[1] + as_[2] + as_[3];
        float S2 = as2_[0] + as2_[1] + as2_[2] + as2_[3];
        float mean = S / (float)LL;
        float var = (S2 - (float)LL * mean * mean) / (float)(LL - 1);
        var = fmaxf(var, 0.f);
        float inv = 1.f / (sqrtf(var) + EPSV);
        wsf[row] = inv;
        wsf[1280 + row] = -mean * inv;
    }
}

__global__ __launch_bounds__(256) void prefix_kernel(const int* __restrict__ lengths,
                                                     const int* __restrict__ ncis,
                                                     int* __restrict__ wbase,
                                                     int* __restrict__ cbase) {
    __shared__ int s1[NK], s2[NK];
    int k = threadIdx.x;
    int v1 = lengths[k] * ncis[k];
    int v2 = ncis[k];
    s1[k] = v1; s2[k] = v2;
    for (int off = 1; off < NK; off <<= 1) {
        __syncthreads();
        int a = (k >= off) ? s1[k - off] : 0;
        int b = (k >= off) ? s2[k - off] : 0;
        __syncthreads();
        s1[k] += a; s2[k] += b;
    }
    __syncthreads();
    wbase[k] = s1[k] - v1;
    cbase[k] = s2[k] - v2;
}

// ====== S: d <= 16 — wave-private LDS tile, no barriers, float4 staging ======
template <int LEN>
__device__ __forceinline__ void conv_S(
    const float* __restrict__ x, float* __restrict__ xw,
    const float* __restrict__ wsmR, const float* __restrict__ wsmS,
    const int* __restrict__ choff, const float* __restrict__ cinv,
    const float* __restrict__ csh,
    int d, int ms, int Lout, int nci, float biasE, float biasI,
    int wu, int lane, int& cnt, float& mx) {
    constexpr int W = GS2 + LEN - 1;
    const int qpt = 64 / d;
    const int MT = qpt * GS2;
    const int stot = d * (MT + LEN - 1);          // <= 1120 (d<=16)
    const int nit4 = (stot + 3 + 255) >> 8;       // <= 5 (wave-uniform)
    const int nitS = (stot + 3 + 63) >> 6;        // <= 18 (wave-uniform)
    const int Qmax = (Lout + d - 1) / d;
    const int nqt = (Qmax + MT - 1) / MT;
    int qi = lane / d, rho = lane - qi * d;
    bool act = qi < qpt;
    int a0 = act ? qi * GS2 * d + rho : 0;
    float rv[28];

    for (int j = wu; j < nqt; j += 4) {
        int qt = j * MT;
        int tb = (qt - ms) * d;
        int off = tb & 3, base = tb - off;
        bool interior = (base >= 0) && (base + (nit4 << 8) <= LL);
        float acc[GS2];
#pragma unroll
        for (int g = 0; g < GS2; ++g) acc[g] = 0.f;

        if (interior) {
            {
                const float* xp = x + choff[0] + base + 4 * lane;
#pragma unroll
                for (int it = 0; it < 7; ++it)
                    if (it < nit4) *(float4*)&rv[4 * it] = *(const float4*)(xp + (it << 8));
            }
            for (int ci = 0; ci < nci; ++ci) {
#pragma unroll
                for (int it = 0; it < 7; ++it)
                    if (it < nit4) *(float4*)&xw[4 * lane + (it << 8)] = *(const float4*)&rv[4 * it];
                if (ci + 1 < nci) {
                    const float* xp = x + choff[ci + 1] + base + 4 * lane;
#pragma unroll
                    for (int it = 0; it < 7; ++it)
                        if (it < nit4) *(float4*)&rv[4 * it] = *(const float4*)(xp + (it << 8));
                }
                float wreg[WROW];
                const float4* wv4 = (const float4*)&wsmS[ci * WROW];
#pragma unroll
                for (int u = 0; u < (LEN + 3) / 4; ++u) {
                    float4 w4 = wv4[u];
                    wreg[4 * u + 0] = w4.x; wreg[4 * u + 1] = w4.y;
                    wreg[4 * u + 2] = w4.z; wreg[4 * u + 3] = w4.w;
                }
                float win[W];
                int a = off + a0;
#pragma unroll
                for (int i = 0; i < W; ++i) { win[i] = xw[a]; a += d; }
                __builtin_amdgcn_s_setprio(1);
#pragma unroll
                for (int jj = 0; jj < LEN; ++jj)
#pragma unroll
                    for (int g = 0; g < GS2; ++g)
                        acc[g] = fmaf(wreg[jj], win[g + jj], acc[g]);
                __builtin_amdgcn_s_setprio(0);
            }
        } else {
            // edge: clamped scalar prefetch, normalize+zero at write, raw weights
            {
                const float* xc = x + choff[0];
#pragma unroll
                for (int it = 0; it < 26; ++it)
                    if (it < nitS) {
                        int t = base + (it << 6) + lane;
                        t = t < 0 ? 0 : (t > LL - 1 ? LL - 1 : t);
                        rv[it] = xc[t];
                    }
            }
            for (int ci = 0; ci < nci; ++ci) {
                float inv = cinv[ci], sh = csh[ci];
#pragma unroll
                for (int it = 0; it < 26; ++it)
                    if (it < nitS) {
                        int t = base + (it << 6) + lane;
                        float v = ((unsigned)t < (unsigned)LL) ? fmaf(rv[it], inv, sh) : 0.f;
                        xw[(it << 6) + lane] = v;
                    }
                if (ci + 1 < nci) {
                    const float* xc = x + choff[ci + 1];
#pragma unroll
                    for (int it = 0; it < 26; ++it)
                        if (it < nitS) {
                            int t = base + (it << 6) + lane;
                            t = t < 0 ? 0 : (t > LL - 1 ? LL - 1 : t);
                            rv[it] = xc[t];
                        }
                }
                float wreg[WROW];
                const float4* wv4 = (const float4*)&wsmR[ci * WROW];
#pragma unroll
                for (int u = 0; u < (LEN + 3) / 4; ++u) {
                    float4 w4 = wv4[u];
                    wreg[4 * u + 0] = w4.x; wreg[4 * u + 1] = w4.y;
                    wreg[4 * u + 2] = w4.z; wreg[4 * u + 3] = w4.w;
                }
                float win[W];
                int a = off + a0;
#pragma unroll
                for (int i = 0; i < W; ++i) { win[i] = xw[a]; a += d; }
                __builtin_amdgcn_s_setprio(1);
#pragma unroll
                for (int jj = 0; jj < LEN; ++jj)
#pragma unroll
                    for (int g = 0; g < GS2; ++g)
                        acc[g] = fmaf(wreg[jj], win[g + jj], acc[g]);
                __builtin_amdgcn_s_setprio(0);
            }
        }

        float bt = interior ? biasI : biasE;
        if (act) {
            int qb = qt + qi * GS2;
            if ((qb + GS2) * d <= Lout) {
                float am = acc[0];
#pragma unroll
                for (int g = 1; g < GS2; ++g) am = fmaxf(am, acc[g]);
                mx = fmaxf(mx, am + bt);
                float nb = -bt;
#pragma unroll
                for (int g = 0; g < GS2; ++g) cnt += (acc[g] > nb) ? 1 : 0;
            } else {
#pragma unroll
                for (int g = 0; g < GS2; ++g) {
                    int t = (qb + g) * d + rho;
                    if (t < Lout) {
                        float y = acc[g] + bt;
                        cnt += (y > 0.f) ? 1 : 0;
                        mx = fmaxf(mx, y);
                    }
                }
            }
        }
    }
}

// ====== T: d > 16 — pure-register windows, flat index (100% lane util) ======
template <int LEN, int GG>
__device__ __forceinline__ void conv_T(
    const float* __restrict__ x,
    const float* __restrict__ wsmR, const float* __restrict__ wsmS,
    const int* __restrict__ choff, const float* __restrict__ cinv,
    const float* __restrict__ csh,
    int d, int ms, int Lout, int nci, float biasE, float biasI,
    int wu, int lane, int& cnt, float& mx) {
    constexpr int M = GG + LEN - 1;
    const int Qmax = (Lout + d - 1) / d;
    const int nqt = (Qmax + GG - 1) / GG;
    const int NT = d * nqt;   // flat work items: f = qi*d + rho

    for (int f0 = wu * 64; f0 < NT; f0 += 256) {
        int f = f0 + lane;
        bool active = f < NT;
        int fc = active ? f : NT - 1;
        unsigned qi = (unsigned)fc / (unsigned)d;
        int rho = fc - (int)qi * d;
        int qb0 = (int)qi * GG;
        int tl = (qb0 - ms) * d + rho;
        bool laneInt = (tl >= 0) && (tl + (M - 1) * d < LL);
        bool interior = __all(laneInt);
        float acc[GG];
#pragma unroll
        for (int g = 0; g < GG; ++g) acc[g] = 0.f;

        float rA[M], rB[M];

        if (interior) {
            {
                const float* xc = x + choff[0];
                int t = tl;
#pragma unroll
                for (int m = 0; m < M; ++m) { rA[m] = xc[t]; t += d; }
            }
            int ci = 0;
            while (true) {
                if (ci + 1 < nci) {
                    const float* xc = x + choff[ci + 1];
                    int t = tl;
#pragma unroll
                    for (int m = 0; m < M; ++m) { rB[m] = xc[t]; t += d; }
                }
                {
                    float wreg[WROW];
                    const float4* wv4 = (const float4*)&wsmS[ci * WROW];
#pragma unroll
                    for (int u = 0; u < (LEN + 3) / 4; ++u) {
                        float4 w4 = wv4[u];
                        wreg[4 * u + 0] = w4.x; wreg[4 * u + 1] = w4.y;
                        wreg[4 * u + 2] = w4.z; wreg[4 * u + 3] = w4.w;
                    }
                    __builtin_amdgcn_s_setprio(1);
#pragma unroll
                    for (int jj = 0; jj < LEN; ++jj)
#pragma unroll
                        for (int g = 0; g < GG; ++g)
                            acc[g] = fmaf(wreg[jj], rA[g + jj], acc[g]);
                    __builtin_amdgcn_s_setprio(0);
                }
                ++ci; if (ci >= nci) break;
                if (ci + 1 < nci) {
                    const float* xc = x + choff[ci + 1];
                    int t = tl;
#pragma unroll
                    for (int m = 0; m < M; ++m) { rA[m] = xc[t]; t += d; }
                }
                {
                    float wreg[WROW];
                    const float4* wv4 = (const float4*)&wsmS[ci * WROW];
#pragma unroll
                    for (int u = 0; u < (LEN + 3) / 4; ++u) {
                        float4 w4 = wv4[u];
                        wreg[4 * u + 0] = w4.x; wreg[4 * u + 1] = w4.y;
                        wreg[4 * u + 2] = w4.z; wreg[4 * u + 3] = w4.w;
                    }
                    __builtin_amdgcn_s_setprio(1);
#pragma unroll
                    for (int jj = 0; jj < LEN; ++jj)
#pragma unroll
                        for (int g = 0; g < GG; ++g)
                            acc[g] = fmaf(wreg[jj], rB[g + jj], acc[g]);
                    __builtin_amdgcn_s_setprio(0);
                }
                ++ci; if (ci >= nci) break;
            }
        } else {
            {
                const float* xc = x + choff[0];
                int t = tl;
#pragma unroll
                for (int m = 0; m < M; ++m) {
                    int tc = t < 0 ? 0 : (t > LL - 1 ? LL - 1 : t);
                    rA[m] = xc[tc]; t += d;
                }
            }
            int ci = 0;
            while (true) {
                if (ci + 1 < nci) {
                    const float* xc = x + choff[ci + 1];
                    int t = tl;
#pragma unroll
                    for (int m = 0; m < M; ++m) {
                        int tc = t < 0 ? 0 : (t > LL - 1 ? LL - 1 : t);
                        rB[m] = xc[tc]; t += d;
                    }
                }
                {
                    float inv = cinv[ci], sh = csh[ci];
                    int t = tl;
#pragma unroll
                    for (int m = 0; m < M; ++m) {
                        rA[m] = ((unsigned)t < (unsigned)LL) ? fmaf(rA[m], inv, sh) : 0.f;
                        t += d;
                    }
                    float wreg[WROW];
                    const float4* wv4 = (const float4*)&wsmR[ci * WROW];
#pragma unroll
                    for (int u = 0; u < (LEN + 3) / 4; ++u) {
                        float4 w4 = wv4[u];
                        wreg[4 * u + 0] = w4.x; wreg[4 * u + 1] = w4.y;
                        wreg[4 * u + 2] = w4.z; wreg[4 * u + 3] = w4.w;
                    }
                    __builtin_amdgcn_s_setprio(1);
#pragma unroll
                    for (int jj = 0; jj < LEN; ++jj)
#pragma unroll
                        for (int g = 0; g < GG; ++g)
                            acc[g] = fmaf(wreg[jj], rA[g + jj], acc[g]);
                    __builtin_amdgcn_s_setprio(0);
                }
                ++ci; if (ci >= nci) break;
                if (ci + 1 < nci) {
                    const float* xc = x + choff[ci + 1];
                    int t = tl;
#pragma unroll
                    for (int m = 0; m < M; ++m) {
                        int tc = t < 0 ? 0 : (t > LL - 1 ? LL - 1 : t);
                        rA[m] = xc[tc]; t += d;
                    }
                }
                {
                    float inv = cinv[ci], sh = csh[ci];
                    int t = tl;
#pragma unroll
                    for (int m = 0; m < M; ++m) {
                        rB[m] = ((unsigned)t < (unsigned)LL) ? fmaf(rB[m], inv, sh) : 0.f;
                        t += d;
                    }
                    float wreg[WROW];
                    const float4* wv4 = (const float4*)&wsmR[ci * WROW];
#pragma unroll
                    for (int u = 0; u < (LEN + 3) / 4; ++u) {
                        float4 w4 = wv4[u];
                        wreg[4 * u + 0] = w4.x; wreg[4 * u + 1] = w4.y;
                        wreg[4 * u + 2] = w4.z; wreg[4 * u + 3] = w4.w;
                    }
                    __builtin_amdgcn_s_setprio(1);
#pragma unroll
                    for (int jj = 0; jj < LEN; ++jj)
#pragma unroll
                        for (int g = 0; g < GG; ++g)
                            acc[g] = fmaf(wreg[jj], rB[g + jj], acc[g]);
                    __builtin_amdgcn_s_setprio(0);
                }
                ++ci; if (ci >= nci) break;
            }
        }

        float bt = interior ? biasI : biasE;
        if (active) {
            if ((qb0 + GG) * d <= Lout) {
                float am = acc[0];
#pragma unroll
                for (int g = 1; g < GG; ++g) am = fmaxf(am, acc[g]);
                mx = fmaxf(mx, am + bt);
                float nb = -bt;
#pragma unroll
                for (int g = 0; g < GG; ++g) cnt += (acc[g] > nb) ? 1 : 0;
            } else {
#pragma unroll
                for (int g = 0; g < GG; ++g) {
                    int t = (qb0 + g) * d + rho;
                    if (t < Lout) {
                        float y = acc[g] + bt;
                        cnt += (y > 0.f) ? 1 : 0;
                        mx = fmaxf(mx, y);
                    }
                }
            }
        }
    }
}

__global__ __launch_bounds__(256) void conv_kernel(
    const float* __restrict__ x, const float* __restrict__ weights,
    const float* __restrict__ biases,
    const int* __restrict__ lengths, const int* __restrict__ dil,
    const int* __restrict__ pad, const int* __restrict__ ncis,
    const int* __restrict__ chidx,
    const float* __restrict__ wsf, const int* __restrict__ wbase,
    const int* __restrict__ cbase, float* __restrict__ out) {
    int k = blockIdx.x, b = blockIdx.y;
    __shared__ __align__(16) float xl[4 * XW];
    __shared__ __align__(16) float wsmR[CC * WROW];
    __shared__ __align__(16) float wsmS[CC * WROW];
    __shared__ int choff[CC];
    __shared__ float cinv[CC], csh[CC];
    __shared__ float rm[4];
    __shared__ int rc[4];

    int tid = threadIdx.x;
    int len = lengths[k], d = dil[k], p = pad[k], nci = ncis[k];
    int wb = wbase[k], cb = cbase[k];

    if (tid < nci) {
        int ch = chidx[cb + tid];
        choff[tid] = (b * CC + ch) * LL;
        cinv[tid] = wsf[b * CC + ch];
        csh[tid] = wsf[1280 + b * CC + ch];
    }
    __syncthreads();
    for (int i = tid; i < nci * WROW; i += 256) {
        int ci = i / WROW, jj = i - ci * WROW;
        float wv = (jj < len) ? weights[wb + ci * len + jj] : 0.f;
        wsmR[i] = wv;
        wsmS[i] = wv * cinv[ci];
    }
    __syncthreads();

    float csum = 0.f;
    for (int ci = 0; ci < nci; ++ci) {
        float sw = 0.f;
        for (int jj = 0; jj < WROW; ++jj) sw += wsmR[ci * WROW + jj];
        csum += csh[ci] * sw;
    }

    int span = (len - 1) * d;
    int Lout = LL + 2 * p - span;
    int ms = p / d;
    float biasE = biases[k];
    float biasI = biasE + csum;
    int Qmax = (Lout + d - 1) / d;

    int wu = tid >> 6;
    int lane = tid & 63;
    float* xw = xl + wu * XW;
    int cnt = 0;
    float mx = -3.4e38f;

    if (d <= 16) {
        switch (len) {
            case 7:  conv_S<7>(x, xw, wsmR, wsmS, choff, cinv, csh, d, ms, Lout, nci, biasE, biasI, wu, lane, cnt, mx); break;
            case 9:  conv_S<9>(x, xw, wsmR, wsmS, choff, cinv, csh, d, ms, Lout, nci, biasE, biasI, wu, lane, cnt, mx); break;
            default: conv_S<11>(x, xw, wsmR, wsmS, choff, cinv, csh, d, ms, Lout, nci, biasE, biasI, wu, lane, cnt, mx); break;
        }
    } else if (Qmax > 12) {
        switch (len) {
            case 7:  conv_T<7, 16>(x, wsmR, wsmS, choff, cinv, csh, d, ms, Lout, nci, biasE, biasI, wu, lane, cnt, mx); break;
            case 9:  conv_T<9, 16>(x, wsmR, wsmS, choff, cinv, csh, d, ms, Lout, nci, biasE, biasI, wu, lane, cnt, mx); break;
            default: conv_T<11, 16>(x, wsmR, wsmS, choff, cinv, csh, d, ms, Lout, nci, biasE, biasI, wu, lane, cnt, mx); break;
        }
    } else {
        switch (len) {
            case 7:  conv_T<7, 4>(x, wsmR, wsmS, choff, cinv, csh, d, ms, Lout, nci, biasE, biasI, wu, lane, cnt, mx); break;
            case 9:  conv_T<9, 4>(x, wsmR, wsmS, choff, cinv, csh, d, ms, Lout, nci, biasE, biasI, wu, lane, cnt, mx); break;
            default: conv_T<11, 4>(x, wsmR, wsmS, choff, cinv, csh, d, ms, Lout, nci, biasE, biasI, wu, lane, cnt, mx); break;
        }
    }
    block_finish(cnt, mx, rm, rc, Lout, out, b, k);
}

extern "C" void kernel_launch(void* const* d_in, const int* in_sizes, int n_in,
                              void* d_out, int out_size, void* d_ws, size_t ws_size,
                              hipStream_t stream) {
    const float* x = (const float*)d_in[0];
    const float* weights = (const float*)d_in[1];
    const float* biases = (const float*)d_in[2];
    const int* lengths = (const int*)d_in[3];
    const int* dil = (const int*)d_in[4];
    const int* pad = (const int*)d_in[5];
    const int* ncis = (const int*)d_in[6];
    const int* chidx = (const int*)d_in[7];
    float* out = (float*)d_out;

    float* wsf = (float*)d_ws;
    int* wbase = (int*)((char*)d_ws + 2560 * sizeof(float));
    int* cbase = wbase + NK;

    stats_kernel<<<dim3(BB * CC), dim3(256), 0, stream>>>(x, wsf);
    prefix_kernel<<<dim3(1), dim3(256), 0, stream>>>(lengths, ncis, wbase, cbase);
    dim3 grid(NK, BB);
    conv_kernel<<<grid, dim3(256), 0, stream>>>(x, weights, biases, lengths, dil,
                                                pad, ncis, chidx, wsf, wbase,
                                                cbase, out);
}

// Round 17
// 1887.043 us; speedup vs baseline: 3.0020x; 1.1728x over previous
//
#include <hip/hip_runtime.h>

#define NK 256
#define BB 128
#define CC 10
#define LL 16384
#define EPSV 1e-10f
#define GS2 15
#define XW 1280
#define WROW 12

__device__ __forceinline__ void block_finish(int cnt, float mx,
                                             float* rm, int* rc,
                                             int Lout, float* out, int b, int k) {
    int tid = threadIdx.x;
    for (int off = 32; off; off >>= 1) {
        mx = fmaxf(mx, __shfl_down(mx, off));
        cnt += __shfl_down(cnt, off);
    }
    int wv = tid >> 6, ln = tid & 63;
    if (ln == 0) { rm[wv] = mx; rc[wv] = cnt; }
    __syncthreads();
    if (tid == 0) {
#pragma unroll
        for (int i = 1; i < 4; ++i) { mx = fmaxf(mx, rm[i]); cnt += rc[i]; }
        size_t o = (size_t)b * (2 * NK) + 2 * k;
        out[o] = (float)cnt / (float)Lout;
        out[o + 1] = mx;
    }
}

__global__ __launch_bounds__(256) void stats_kernel(const float* __restrict__ x,
                                                    float* __restrict__ wsf) {
    int row = blockIdx.x;
    const float4* x4 = (const float4*)(x + (size_t)row * LL);
    int tid = threadIdx.x;
    float s = 0.f, s2 = 0.f;
    for (int i = tid; i < LL / 4; i += 256) {
        float4 v = x4[i];
        s += v.x + v.y + v.z + v.w;
        s2 += v.x * v.x + v.y * v.y + v.z * v.z + v.w * v.w;
    }
    for (int off = 32; off; off >>= 1) {
        s += __shfl_down(s, off);
        s2 += __shfl_down(s2, off);
    }
    __shared__ float as_[4], as2_[4];
    int wv = tid >> 6, ln = tid & 63;
    if (ln == 0) { as_[wv] = s; as2_[wv] = s2; }
    __syncthreads();
    if (tid == 0) {
        float S = as_[0] + as_[1] + as_[2] + as_[3];
        float S2 = as2_[0] + as2_[1] + as2_[2] + as2_[3];
        float mean = S / (float)LL;
        float var = (S2 - (float)LL * mean * mean) / (float)(LL - 1);
        var = fmaxf(var, 0.f);
        float inv = 1.f / (sqrtf(var) + EPSV);
        wsf[row] = inv;
        wsf[1280 + row] = -mean * inv;
    }
}

__global__ __launch_bounds__(256) void prefix_kernel(const int* __restrict__ lengths,
                                                     const int* __restrict__ ncis,
                                                     const int* __restrict__ dil,
                                                     const int* __restrict__ pad,
                                                     int* __restrict__ wbase,
                                                     int* __restrict__ cbase,
                                                     int* __restrict__ perm) {
    __shared__ int s1[NK], s2[NK], swk[NK];
    int k = threadIdx.x;
    int len = lengths[k], d = dil[k], p = pad[k];
    int v1 = len * ncis[k];
    int v2 = ncis[k];
    int Lout = LL + 2 * p - (len - 1) * d;
    int Qmax = (Lout + d - 1) / d;
    int wk = v2 * Qmax;
    swk[k] = wk;
    s1[k] = v1; s2[k] = v2;
    for (int off = 1; off < NK; off <<= 1) {
        __syncthreads();
        int a = (k >= off) ? s1[k - off] : 0;
        int b = (k >= off) ? s2[k - off] : 0;
        __syncthreads();
        s1[k] += a; s2[k] += b;
    }
    __syncthreads();
    wbase[k] = s1[k] - v1;
    cbase[k] = s2[k] - v2;
    int rank = 0;
    for (int j = 0; j < NK; ++j) {
        int wj = swk[j];
        rank += (wj > wk) || (wj == wk && j < k) ? 1 : 0;
    }
    perm[rank] = k;
}

// ====== S: d <= 16 (D constexpr) — wave-private LDS, no barriers ============
template <int LEN, int D>
__device__ __forceinline__ void conv_S(
    const float* __restrict__ x, float* __restrict__ xw,
    const float* __restrict__ wsmR, const float* __restrict__ wsmS,
    const int* __restrict__ choff, const float* __restrict__ cinv,
    const float* __restrict__ csh,
    int ms, int Lout, int nci, float biasE, float biasI,
    int wu, int lane, int& cnt, float& mx) {
    constexpr int W = GS2 + LEN - 1;
    constexpr int qpt = 64 / D;
    constexpr int MT = qpt * GS2;
    constexpr int stot = D * (MT + LEN - 1);       // <= 1120
    constexpr int nit4 = (stot + 3 + 255) >> 8;    // <= 5
    constexpr int nitS = (stot + 3 + 63) >> 6;     // <= 18
    constexpr int RVN = (4 * nit4 > nitS) ? 4 * nit4 : nitS;
    const int Qmax = (Lout + D - 1) / D;
    const int nqt = (Qmax + MT - 1) / MT;
    int qi = lane / D, rho = lane - qi * D;
    bool act = qi < qpt;
    int a0 = act ? qi * GS2 * D + rho : 0;
    float rv[RVN];

    for (int j = wu; j < nqt; j += 4) {
        int qt = j * MT;
        int tb = (qt - ms) * D;
        int off = tb & 3, base = tb - off;
        bool interior = (base >= 0) && (base + (nit4 << 8) <= LL);
        float acc[GS2];
#pragma unroll
        for (int g = 0; g < GS2; ++g) acc[g] = 0.f;

        if (interior) {
            {
                const float* xp = x + choff[0] + base + 4 * lane;
#pragma unroll
                for (int it = 0; it < nit4; ++it)
                    *(float4*)&rv[4 * it] = *(const float4*)(xp + (it << 8));
            }
            for (int ci = 0; ci < nci; ++ci) {
#pragma unroll
                for (int it = 0; it < nit4; ++it)
                    *(float4*)&xw[4 * lane + (it << 8)] = *(const float4*)&rv[4 * it];
                if (ci + 1 < nci) {
                    const float* xp = x + choff[ci + 1] + base + 4 * lane;
#pragma unroll
                    for (int it = 0; it < nit4; ++it)
                        *(float4*)&rv[4 * it] = *(const float4*)(xp + (it << 8));
                }
                float wreg[WROW];
                const float4* wv4 = (const float4*)&wsmS[ci * WROW];
#pragma unroll
                for (int u = 0; u < (LEN + 3) / 4; ++u) {
                    float4 w4 = wv4[u];
                    wreg[4 * u + 0] = w4.x; wreg[4 * u + 1] = w4.y;
                    wreg[4 * u + 2] = w4.z; wreg[4 * u + 3] = w4.w;
                }
                float win[W];
                int ab = off + a0;
#pragma unroll
                for (int i = 0; i < W; ++i) win[i] = xw[ab + i * D];
                __builtin_amdgcn_s_setprio(1);
#pragma unroll
                for (int jj = 0; jj < LEN; ++jj)
#pragma unroll
                    for (int g = 0; g < GS2; ++g)
                        acc[g] = fmaf(wreg[jj], win[g + jj], acc[g]);
                __builtin_amdgcn_s_setprio(0);
            }
        } else {
            // edge: clamped scalar prefetch, normalize+zero at write, raw weights
            {
                const float* xc = x + choff[0];
#pragma unroll
                for (int it = 0; it < nitS; ++it) {
                    int t = base + (it << 6) + lane;
                    t = t < 0 ? 0 : (t > LL - 1 ? LL - 1 : t);
                    rv[it] = xc[t];
                }
            }
            for (int ci = 0; ci < nci; ++ci) {
                float inv = cinv[ci], sh = csh[ci];
#pragma unroll
                for (int it = 0; it < nitS; ++it) {
                    int t = base + (it << 6) + lane;
                    float v = ((unsigned)t < (unsigned)LL) ? fmaf(rv[it], inv, sh) : 0.f;
                    xw[(it << 6) + lane] = v;
                }
                if (ci + 1 < nci) {
                    const float* xc = x + choff[ci + 1];
#pragma unroll
                    for (int it = 0; it < nitS; ++it) {
                        int t = base + (it << 6) + lane;
                        t = t < 0 ? 0 : (t > LL - 1 ? LL - 1 : t);
                        rv[it] = xc[t];
                    }
                }
                float wreg[WROW];
                const float4* wv4 = (const float4*)&wsmR[ci * WROW];
#pragma unroll
                for (int u = 0; u < (LEN + 3) / 4; ++u) {
                    float4 w4 = wv4[u];
                    wreg[4 * u + 0] = w4.x; wreg[4 * u + 1] = w4.y;
                    wreg[4 * u + 2] = w4.z; wreg[4 * u + 3] = w4.w;
                }
                float win[W];
                int ab = off + a0;
#pragma unroll
                for (int i = 0; i < W; ++i) win[i] = xw[ab + i * D];
                __builtin_amdgcn_s_setprio(1);
#pragma unroll
                for (int jj = 0; jj < LEN; ++jj)
#pragma unroll
                    for (int g = 0; g < GS2; ++g)
                        acc[g] = fmaf(wreg[jj], win[g + jj], acc[g]);
                __builtin_amdgcn_s_setprio(0);
            }
        }

        float bt = interior ? biasI : biasE;
        if (act) {
            int qb = qt + qi * GS2;
            if ((qb + GS2) * D <= Lout) {
                float am = acc[0];
#pragma unroll
                for (int g = 1; g < GS2; ++g) am = fmaxf(am, acc[g]);
                mx = fmaxf(mx, am + bt);
                float nb = -bt;
#pragma unroll
                for (int g = 0; g < GS2; ++g) cnt += (acc[g] > nb) ? 1 : 0;
            } else {
#pragma unroll
                for (int g = 0; g < GS2; ++g) {
                    int t = (qb + g) * D + rho;
                    if (t < Lout) {
                        float y = acc[g] + bt;
                        cnt += (y > 0.f) ? 1 : 0;
                        mx = fmaxf(mx, y);
                    }
                }
            }
        }
    }
}

template <int LEN>
__device__ __forceinline__ void conv_S_d(
    const float* __restrict__ x, float* __restrict__ xw,
    const float* __restrict__ wsmR, const float* __restrict__ wsmS,
    const int* __restrict__ choff, const float* __restrict__ cinv,
    const float* __restrict__ csh,
    int d, int ms, int Lout, int nci, float biasE, float biasI,
    int wu, int lane, int& cnt, float& mx) {
#define SC(DD) case DD: conv_S<LEN, DD>(x, xw, wsmR, wsmS, choff, cinv, csh, ms, Lout, nci, biasE, biasI, wu, lane, cnt, mx); break;
    switch (d) {
        SC(1) SC(2) SC(3) SC(4) SC(5) SC(6) SC(7) SC(8)
        SC(9) SC(10) SC(11) SC(12) SC(13) SC(14) SC(15) SC(16)
    }
#undef SC
}

// ====== T: d > 16 — pure-register windows, flat index (100% lane util) ======
template <int LEN, int GG>
__device__ __forceinline__ void conv_T(
    const float* __restrict__ x,
    const float* __restrict__ wsmR, const float* __restrict__ wsmS,
    const int* __restrict__ choff, const float* __restrict__ cinv,
    const float* __restrict__ csh,
    int d, int ms, int Lout, int nci, float biasE, float biasI,
    int wu, int lane, int& cnt, float& mx) {
    constexpr int M = GG + LEN - 1;
    const int Qmax = (Lout + d - 1) / d;
    const int nqt = (Qmax + GG - 1) / GG;
    const int NT = d * nqt;   // flat work items: f = qi*d + rho

    for (int f0 = wu * 64; f0 < NT; f0 += 256) {
        int f = f0 + lane;
        bool active = f < NT;
        int fc = active ? f : NT - 1;
        unsigned qi = (unsigned)fc / (unsigned)d;
        int rho = fc - (int)qi * d;
        int qb0 = (int)qi * GG;
        int tl = (qb0 - ms) * d + rho;
        bool laneInt = (tl >= 0) && (tl + (M - 1) * d < LL);
        bool interior = __all(laneInt);
        float acc[GG];
#pragma unroll
        for (int g = 0; g < GG; ++g) acc[g] = 0.f;

        float rA[M], rB[M];

        if (interior) {
            {
                const float* xc = x + choff[0];
                int t = tl;
#pragma unroll
                for (int m = 0; m < M; ++m) { rA[m] = xc[t]; t += d; }
            }
            int ci = 0;
            while (true) {
                if (ci + 1 < nci) {
                    const float* xc = x + choff[ci + 1];
                    int t = tl;
#pragma unroll
                    for (int m = 0; m < M; ++m) { rB[m] = xc[t]; t += d; }
                }
                {
                    float wreg[WROW];
                    const float4* wv4 = (const float4*)&wsmS[ci * WROW];
#pragma unroll
                    for (int u = 0; u < (LEN + 3) / 4; ++u) {
                        float4 w4 = wv4[u];
                        wreg[4 * u + 0] = w4.x; wreg[4 * u + 1] = w4.y;
                        wreg[4 * u + 2] = w4.z; wreg[4 * u + 3] = w4.w;
                    }
                    __builtin_amdgcn_s_setprio(1);
#pragma unroll
                    for (int jj = 0; jj < LEN; ++jj)
#pragma unroll
                        for (int g = 0; g < GG; ++g)
                            acc[g] = fmaf(wreg[jj], rA[g + jj], acc[g]);
                    __builtin_amdgcn_s_setprio(0);
                }
                ++ci; if (ci >= nci) break;
                if (ci + 1 < nci) {
                    const float* xc = x + choff[ci + 1];
                    int t = tl;
#pragma unroll
                    for (int m = 0; m < M; ++m) { rA[m] = xc[t]; t += d; }
                }
                {
                    float wreg[WROW];
                    const float4* wv4 = (const float4*)&wsmS[ci * WROW];
#pragma unroll
                    for (int u = 0; u < (LEN + 3) / 4; ++u) {
                        float4 w4 = wv4[u];
                        wreg[4 * u + 0] = w4.x; wreg[4 * u + 1] = w4.y;
                        wreg[4 * u + 2] = w4.z; wreg[4 * u + 3] = w4.w;
                    }
                    __builtin_amdgcn_s_setprio(1);
#pragma unroll
                    for (int jj = 0; jj < LEN; ++jj)
#pragma unroll
                        for (int g = 0; g < GG; ++g)
                            acc[g] = fmaf(wreg[jj], rB[g + jj], acc[g]);
                    __builtin_amdgcn_s_setprio(0);
                }
                ++ci; if (ci >= nci) break;
            }
        } else {
            {
                const float* xc = x + choff[0];
                int t = tl;
#pragma unroll
                for (int m = 0; m < M; ++m) {
                    int tc = t < 0 ? 0 : (t > LL - 1 ? LL - 1 : t);
                    rA[m] = xc[tc]; t += d;
                }
            }
            int ci = 0;
            while (true) {
                if (ci + 1 < nci) {
                    const float* xc = x + choff[ci + 1];
                    int t = tl;
#pragma unroll
                    for (int m = 0; m < M; ++m) {
                        int tc = t < 0 ? 0 : (t > LL - 1 ? LL - 1 : t);
                        rB[m] = xc[tc]; t += d;
                    }
                }
                {
                    float inv = cinv[ci], sh = csh[ci];
                    int t = tl;
#pragma unroll
                    for (int m = 0; m < M; ++m) {
                        rA[m] = ((unsigned)t < (unsigned)LL) ? fmaf(rA[m], inv, sh) : 0.f;
                        t += d;
                    }
                    float wreg[WROW];
                    const float4* wv4 = (const float4*)&wsmR[ci * WROW];
#pragma unroll
                    for (int u = 0; u < (LEN + 3) / 4; ++u) {
                        float4 w4 = wv4[u];
                        wreg[4 * u + 0] = w4.x; wreg[4 * u + 1] = w4.y;
                        wreg[4 * u + 2] = w4.z; wreg[4 * u + 3] = w4.w;
                    }
                    __builtin_amdgcn_s_setprio(1);
#pragma unroll
                    for (int jj = 0; jj < LEN; ++jj)
#pragma unroll
                        for (int g = 0; g < GG; ++g)
                            acc[g] = fmaf(wreg[jj], rA[g + jj], acc[g]);
                    __builtin_amdgcn_s_setprio(0);
                }
                ++ci; if (ci >= nci) break;
                if (ci + 1 < nci) {
                    const float* xc = x + choff[ci + 1];
                    int t = tl;
#pragma unroll
                    for (int m = 0; m < M; ++m) {
                        int tc = t < 0 ? 0 : (t > LL - 1 ? LL - 1 : t);
                        rA[m] = xc[tc]; t += d;
                    }
                }
                {
                    float inv = cinv[ci], sh = csh[ci];
                    int t = tl;
#pragma unroll
                    for (int m = 0; m < M; ++m) {
                        rB[m] = ((unsigned)t < (unsigned)LL) ? fmaf(rB[m], inv, sh) : 0.f;
                        t += d;
                    }
                    float wreg[WROW];
                    const float4* wv4 = (const float4*)&wsmR[ci * WROW];
#pragma unroll
                    for (int u = 0; u < (LEN + 3) / 4; ++u) {
                        float4 w4 = wv4[u];
                        wreg[4 * u + 0] = w4.x; wreg[4 * u + 1] = w4.y;
                        wreg[4 * u + 2] = w4.z; wreg[4 * u + 3] = w4.w;
                    }
                    __builtin_amdgcn_s_setprio(1);
#pragma unroll
                    for (int jj = 0; jj < LEN; ++jj)
#pragma unroll
                        for (int g = 0; g < GG; ++g)
                            acc[g] = fmaf(wreg[jj], rB[g + jj], acc[g]);
                    __builtin_amdgcn_s_setprio(0);
                }
                ++ci; if (ci >= nci) break;
            }
        }

        float bt = interior ? biasI : biasE;
        if (active) {
            if ((qb0 + GG) * d <= Lout) {
                float am = acc[0];
#pragma unroll
                for (int g = 1; g < GG; ++g) am = fmaxf(am, acc[g]);
                mx = fmaxf(mx, am + bt);
                float nb = -bt;
#pragma unroll
                for (int g = 0; g < GG; ++g) cnt += (acc[g] > nb) ? 1 : 0;
            } else {
#pragma unroll
                for (int g = 0; g < GG; ++g) {
                    int t = (qb0 + g) * d + rho;
                    if (t < Lout) {
                        float y = acc[g] + bt;
                        cnt += (y > 0.f) ? 1 : 0;
                        mx = fmaxf(mx, y);
                    }
                }
            }
        }
    }
}

__global__ __launch_bounds__(256) void conv_kernel(
    const float* __restrict__ x, const float* __restrict__ weights,
    const float* __restrict__ biases,
    const int* __restrict__ lengths, const int* __restrict__ dil,
    const int* __restrict__ pad, const int* __restrict__ ncis,
    const int* __restrict__ chidx,
    const float* __restrict__ wsf, const int* __restrict__ wbase,
    const int* __restrict__ cbase, const int* __restrict__ perm,
    float* __restrict__ out) {
    int k = perm[blockIdx.x];
    int b = blockIdx.y;
    __shared__ __align__(16) float xl[4 * XW];
    __shared__ __align__(16) float wsmR[CC * WROW];
    __shared__ __align__(16) float wsmS[CC * WROW];
    __shared__ int choff[CC];
    __shared__ float cinv[CC], csh[CC];
    __shared__ float rm[4];
    __shared__ int rc[4];

    int tid = threadIdx.x;
    int len = lengths[k], d = dil[k], p = pad[k], nci = ncis[k];
    int wb = wbase[k], cb = cbase[k];

    if (tid < nci) {
        int ch = chidx[cb + tid];
        choff[tid] = (b * CC + ch) * LL;
        cinv[tid] = wsf[b * CC + ch];
        csh[tid] = wsf[1280 + b * CC + ch];
    }
    __syncthreads();
    for (int i = tid; i < nci * WROW; i += 256) {
        int ci = i / WROW, jj = i - ci * WROW;
        float wv = (jj < len) ? weights[wb + ci * len + jj] : 0.f;
        wsmR[i] = wv;
        wsmS[i] = wv * cinv[ci];
    }
    __syncthreads();

    float csum = 0.f;
    for (int ci = 0; ci < nci; ++ci) {
        float sw = 0.f;
        for (int jj = 0; jj < WROW; ++jj) sw += wsmR[ci * WROW + jj];
        csum += csh[ci] * sw;
    }

    int span = (len - 1) * d;
    int Lout = LL + 2 * p - span;
    int ms = p / d;
    float biasE = biases[k];
    float biasI = biasE + csum;
    int Qmax = (Lout + d - 1) / d;

    int wu = tid >> 6;
    int lane = tid & 63;
    float* xw = xl + wu * XW;
    int cnt = 0;
    float mx = -3.4e38f;

    if (d <= 16) {
        switch (len) {
            case 7:  conv_S_d<7>(x, xw, wsmR, wsmS, choff, cinv, csh, d, ms, Lout, nci, biasE, biasI, wu, lane, cnt, mx); break;
            case 9:  conv_S_d<9>(x, xw, wsmR, wsmS, choff, cinv, csh, d, ms, Lout, nci, biasE, biasI, wu, lane, cnt, mx); break;
            default: conv_S_d<11>(x, xw, wsmR, wsmS, choff, cinv, csh, d, ms, Lout, nci, biasE, biasI, wu, lane, cnt, mx); break;
        }
    } else if (Qmax > 12) {
        switch (len) {
            case 7:  conv_T<7, 16>(x, wsmR, wsmS, choff, cinv, csh, d, ms, Lout, nci, biasE, biasI, wu, lane, cnt, mx); break;
            case 9:  conv_T<9, 16>(x, wsmR, wsmS, choff, cinv, csh, d, ms, Lout, nci, biasE, biasI, wu, lane, cnt, mx); break;
            default: conv_T<11, 16>(x, wsmR, wsmS, choff, cinv, csh, d, ms, Lout, nci, biasE, biasI, wu, lane, cnt, mx); break;
        }
    } else {
        switch (len) {
            case 7:  conv_T<7, 4>(x, wsmR, wsmS, choff, cinv, csh, d, ms, Lout, nci, biasE, biasI, wu, lane, cnt, mx); break;
            case 9:  conv_T<9, 4>(x, wsmR, wsmS, choff, cinv, csh, d, ms, Lout, nci, biasE, biasI, wu, lane, cnt, mx); break;
            default: conv_T<11, 4>(x, wsmR, wsmS, choff, cinv, csh, d, ms, Lout, nci, biasE, biasI, wu, lane, cnt, mx); break;
        }
    }
    block_finish(cnt, mx, rm, rc, Lout, out, b, k);
}

extern "C" void kernel_launch(void* const* d_in, const int* in_sizes, int n_in,
                              void* d_out, int out_size, void* d_ws, size_t ws_size,
                              hipStream_t stream) {
    const float* x = (const float*)d_in[0];
    const float* weights = (const float*)d_in[1];
    const float* biases = (const float*)d_in[2];
    const int* lengths = (const int*)d_in[3];
    const int* dil = (const int*)d_in[4];
    const int* pad = (const int*)d_in[5];
    const int* ncis = (const int*)d_in[6];
    const int* chidx = (const int*)d_in[7];
    float* out = (float*)d_out;

    float* wsf = (float*)d_ws;
    int* wbase = (int*)((char*)d_ws + 2560 * sizeof(float));
    int* cbase = wbase + NK;
    int* perm = cbase + NK;

    stats_kernel<<<dim3(BB * CC), dim3(256), 0, stream>>>(x, wsf);
    prefix_kernel<<<dim3(1), dim3(256), 0, stream>>>(lengths, ncis, dil, pad,
                                                     wbase, cbase, perm);
    dim3 grid(NK, BB);
    conv_kernel<<<grid, dim3(256), 0, stream>>>(x, weights, biases, lengths, dil,
                                                pad, ncis, chidx, wsf, wbase,
                                                cbase, perm, out);
}